// Round 1
// baseline (297.047 us; speedup 1.0000x reference)
//
#include <hip/hip_runtime.h>
#include <math.h>

#define S_ 3
#define G_ 8
#define B_ 2048
#define C_ 512
#define P_ 64
#define N_ (S_ * G_ * B_)   // 49152

// ---------------------------------------------------------------------------
// Kernel 0: zero the outputs accumulator region (harness poisons d_out 0xAA)
// ---------------------------------------------------------------------------
__global__ void zero_kernel(float* __restrict__ out, int n) {
    int i = blockIdx.x * blockDim.x + threadIdx.x;
    if (i < n) out[i] = 0.0f;
}

// ---------------------------------------------------------------------------
// Kernel 1: assign = softmax_p( min(2*x.w_p - |x|^2 - |w_p|^2, 0) / sigmoid(sf_p) )
// One block = 64 rows x all 64 centroids. Tiled fp32 GEMM, K-chunks of 32.
// ---------------------------------------------------------------------------
__global__ __launch_bounds__(256) void assign_kernel(
    const float* __restrict__ x,     // [N, 512]
    const float* __restrict__ w,     // [64, 512]
    const float* __restrict__ sf,    // [64]
    float* __restrict__ assign)      // [N, 64]
{
    __shared__ float xs[64][33];     // x tile, +1 pad
    __shared__ float wt[32][65];     // w tile transposed, +1 pad
    __shared__ float lg[64][65];     // logits -> assign scratch
    __shared__ float xsq_s[64];
    __shared__ float csq_s[64];
    __shared__ float rbeta_s[64];

    const int tid = threadIdx.x;
    const int n0  = blockIdx.x * 64;
    const int ty  = tid >> 4;        // 0..15 (row group)
    const int tx  = tid & 15;        // 0..15 (p group)

    if (tid < 64) rbeta_s[tid] = 1.0f + expf(-sf[tid]);   // 1/sigmoid(s)

    float acc[4][4];
#pragma unroll
    for (int i = 0; i < 4; ++i)
#pragma unroll
        for (int j = 0; j < 4; ++j) acc[i][j] = 0.0f;

    float xsq_acc = 0.0f, csq_acc = 0.0f;

    for (int k0 = 0; k0 < C_; k0 += 32) {
        // ---- stage: x tile 64x32 and w tile transposed 32x64 ----
#pragma unroll
        for (int q = 0; q < 2; ++q) {
            int t  = tid + 256 * q;
            int r  = t >> 3;         // 0..63
            int sg = t & 7;          // 0..7 (float4 segment)
            float4 v = *(const float4*)(x + (size_t)(n0 + r) * C_ + k0 + sg * 4);
            xs[r][sg * 4 + 0] = v.x;
            xs[r][sg * 4 + 1] = v.y;
            xs[r][sg * 4 + 2] = v.z;
            xs[r][sg * 4 + 3] = v.w;
            float4 u = *(const float4*)(w + (size_t)r * C_ + k0 + sg * 4);
            wt[sg * 4 + 0][r] = u.x;
            wt[sg * 4 + 1][r] = u.y;
            wt[sg * 4 + 2][r] = u.z;
            wt[sg * 4 + 3][r] = u.w;
        }
        __syncthreads();

        // ---- fused |w_p|^2 and |x|^2 partial sums ----
        if (tid < 64) {
            float s = 0.0f;
#pragma unroll
            for (int k = 0; k < 32; ++k) { float v = wt[k][tid]; s += v * v; }
            csq_acc += s;
        } else if (tid < 128) {
            int r = tid - 64;
            float s = 0.0f;
#pragma unroll
            for (int k = 0; k < 32; ++k) { float v = xs[r][k]; s += v * v; }
            xsq_acc += s;
        }

        // ---- main MACs: 4x4 per thread ----
#pragma unroll
        for (int k = 0; k < 32; ++k) {
            float xv[4], wv[4];
#pragma unroll
            for (int i = 0; i < 4; ++i) xv[i] = xs[ty * 4 + i][k];
#pragma unroll
            for (int j = 0; j < 4; ++j) wv[j] = wt[k][tx * 4 + j];
#pragma unroll
            for (int i = 0; i < 4; ++i)
#pragma unroll
                for (int j = 0; j < 4; ++j) acc[i][j] += xv[i] * wv[j];
        }
        __syncthreads();
    }

    if (tid < 64) csq_s[tid] = csq_acc;
    else if (tid < 128) xsq_s[tid - 64] = xsq_acc;
    __syncthreads();

    // ---- logits (clamped, scaled by 1/beta) into LDS ----
#pragma unroll
    for (int i = 0; i < 4; ++i) {
#pragma unroll
        for (int j = 0; j < 4; ++j) {
            int r = ty * 4 + i, p = tx * 4 + j;
            float v = 2.0f * acc[i][j] - xsq_s[r] - csq_s[p];
            v = fminf(v, 0.0f) * rbeta_s[p];
            lg[r][p] = v;
        }
    }
    __syncthreads();

    // ---- per-row softmax (one thread per row) ----
    if (tid < 64) {
        int r = tid;
        float m = -3.4e38f;
        for (int p = 0; p < 64; ++p) m = fmaxf(m, lg[r][p]);
        float s = 0.0f;
        for (int p = 0; p < 64; ++p) { float e = expf(lg[r][p] - m); lg[r][p] = e; s += e; }
        float inv = 1.0f / s;
        for (int p = 0; p < 64; ++p) lg[r][p] *= inv;
    }
    __syncthreads();

    // ---- coalesced write of assign tile ----
#pragma unroll
    for (int t = 0; t < 16; ++t) {
        int flat = t * 256 + tid;
        int r = flat >> 6, p = flat & 63;
        assign[(size_t)(n0 + r) * P_ + p] = lg[r][p];
    }
}

// ---------------------------------------------------------------------------
// Kernel 2: out[g,p,c] += sum_{rows of graph g} assign[n,p] * x[n,c]
// Grid: (g=8, ctile=8, kchunk=12); 512 rows per block; atomicAdd merge.
// ---------------------------------------------------------------------------
__global__ __launch_bounds__(256) void group_kernel(
    const float* __restrict__ x,       // [N, 512]
    const float* __restrict__ assign,  // [N, 64]
    float* __restrict__ out)           // [8, 64, 512]
{
    __shared__ float As[32][64];
    __shared__ float Fs[32][64];

    const int tid = threadIdx.x;
    const int g   = blockIdx.x;            // 0..7
    const int c0  = blockIdx.y * 64;       // 0..7 -> col tile
    const int kc  = blockIdx.z;            // 0..11
    const int s   = kc >> 2;               // scale 0..2
    const int b0  = (kc & 3) * 512;        // batch offset within graph
    const int tp  = tid >> 4;              // 0..15 (p group)
    const int tc  = tid & 15;              // 0..15 (c group)

    float acc[4][4];
#pragma unroll
    for (int i = 0; i < 4; ++i)
#pragma unroll
        for (int j = 0; j < 4; ++j) acc[i][j] = 0.0f;

    for (int kb = 0; kb < 512; kb += 32) {
        // stage 32 rows of assign (64 wide) and feats (this c-tile, 64 wide)
#pragma unroll
        for (int q = 0; q < 2; ++q) {
            int t  = tid + 256 * q;
            int r  = t >> 4;               // 0..31
            int sg = t & 15;               // 0..15
            int n  = s * (G_ * B_) + g * B_ + b0 + kb + r;
            float4 a4 = *(const float4*)(assign + (size_t)n * P_ + sg * 4);
            *(float4*)&As[r][sg * 4] = a4;
            float4 f4 = *(const float4*)(x + (size_t)n * C_ + c0 + sg * 4);
            *(float4*)&Fs[r][sg * 4] = f4;
        }
        __syncthreads();

#pragma unroll
        for (int k = 0; k < 32; ++k) {
            float4 a4 = *(const float4*)&As[k][tp * 4];
            float4 f4 = *(const float4*)&Fs[k][tc * 4];
            float av[4] = {a4.x, a4.y, a4.z, a4.w};
            float fv[4] = {f4.x, f4.y, f4.z, f4.w};
#pragma unroll
            for (int i = 0; i < 4; ++i)
#pragma unroll
                for (int j = 0; j < 4; ++j) acc[i][j] += av[i] * fv[j];
        }
        __syncthreads();
    }

#pragma unroll
    for (int i = 0; i < 4; ++i) {
#pragma unroll
        for (int j = 0; j < 4; ++j) {
            int p = tp * 4 + i;
            int c = c0 + tc * 4 + j;
            atomicAdd(&out[(size_t)g * (P_ * C_) + (size_t)p * C_ + c], acc[i][j]);
        }
    }
}

// ---------------------------------------------------------------------------
extern "C" void kernel_launch(void* const* d_in, const int* in_sizes, int n_in,
                              void* d_out, int out_size, void* d_ws, size_t ws_size,
                              hipStream_t stream) {
    const float* x  = (const float*)d_in[0];   // node_feats [3, 16384, 512]
    const float* w  = (const float*)d_in[1];   // weight [64, 512]
    const float* sf = (const float*)d_in[2];   // smooth_factor [64]

    float* out    = (float*)d_out;             // outputs [8, 64, 512]
    float* assign = out + (size_t)G_ * P_ * C_; // assign [N, 64]

    // zero the atomic accumulator region
    zero_kernel<<<(G_ * P_ * C_ + 255) / 256, 256, 0, stream>>>(out, G_ * P_ * C_);

    // assign (softmax RBF scores)
    assign_kernel<<<N_ / 64, 256, 0, stream>>>(x, w, sf, assign);

    // per-graph weighted feature sums
    dim3 gridB(G_, C_ / 64, 12);
    group_kernel<<<gridB, 256, 0, stream>>>(x, assign, out);
}

// Round 2
// 199.099 us; speedup vs baseline: 1.4920x; 1.4920x over previous
//
#include <hip/hip_runtime.h>
#include <math.h>

#define S_ 3
#define G_ 8
#define B_ 2048
#define C_ 512
#define P_ 64
#define N_ (S_ * G_ * B_)   // 49152

typedef __attribute__((ext_vector_type(8))) short short8;
typedef __attribute__((ext_vector_type(4))) short short4v;
typedef __attribute__((ext_vector_type(4))) float f32x4;

__device__ __forceinline__ unsigned short f2bf(float f) {
    union { float f; unsigned u; } c; c.f = f;
    unsigned u = c.u;
    u += 0x7fffu + ((u >> 16) & 1u);   // RNE
    return (unsigned short)(u >> 16);
}

// ---------------------------------------------------------------------------
// Kernel 0: zero the outputs accumulator region (harness poisons d_out 0xAA)
// ---------------------------------------------------------------------------
__global__ void zero_kernel(float* __restrict__ out, int n) {
    int i = blockIdx.x * blockDim.x + threadIdx.x;
    if (i < n) out[i] = 0.0f;
}

// ---------------------------------------------------------------------------
// Kernel 1: assign via bf16 MFMA. Block = 64 rows x 64 p, 4 waves.
// NT GEMM: both x-tile and w-tile stored row-major k-contiguous bf16
// (stride 72 keeps ds_read_b128 16B-aligned and ~2-way banks).
// xsq/csq accumulated in fp32 during staging. Wave-parallel softmax.
// ---------------------------------------------------------------------------
__global__ __launch_bounds__(256) void assign_mfma(
    const float* __restrict__ x,     // [N, 512]
    const float* __restrict__ w,     // [64, 512]
    const float* __restrict__ sf,    // [64]
    float* __restrict__ assign)      // [N, 64]
{
    __shared__ __align__(16) short xs[64 * 72];
    __shared__ __align__(16) short ws[64 * 72];
    __shared__ float xsqp[64][16];
    __shared__ float csqp[64][16];
    __shared__ float xsq_s[64], csq_s[64], rbeta_s[64];

    const int t    = threadIdx.x;
    const int n0   = blockIdx.x * 64;
    const int lane = t & 63;
    const int wv   = t >> 6;         // wave id 0..3 -> m-strip
    const int q    = lane >> 4;      // quad
    const int col  = lane & 15;
    const int srow = t >> 4;         // staging row group 0..15
    const int scol = (t & 15) * 4;   // staging float4 col 0..60

    if (t < 64) rbeta_s[t] = 1.0f + expf(-sf[t]);   // 1/sigmoid

    f32x4 acc[4];
#pragma unroll
    for (int i = 0; i < 4; ++i) acc[i] = (f32x4){0.f, 0.f, 0.f, 0.f};

    float xacc[4] = {0.f, 0.f, 0.f, 0.f};
    float wacc[4] = {0.f, 0.f, 0.f, 0.f};

    for (int ch = 0; ch < 8; ++ch) {
        const int k0 = ch * 64;
        // ---- stage x-tile and w-tile (fp32 -> bf16), fuse |.|^2 partials ----
#pragma unroll
        for (int i = 0; i < 4; ++i) {
            int row = srow + 16 * i;
            f32x4 xv = *(const f32x4*)(x + (size_t)(n0 + row) * C_ + k0 + scol);
            xacc[i] += xv.x * xv.x + xv.y * xv.y + xv.z * xv.z + xv.w * xv.w;
            short4v xb = {(short)f2bf(xv.x), (short)f2bf(xv.y),
                          (short)f2bf(xv.z), (short)f2bf(xv.w)};
            *(short4v*)&xs[row * 72 + scol] = xb;

            f32x4 wl = *(const f32x4*)(w + (size_t)row * C_ + k0 + scol);
            wacc[i] += wl.x * wl.x + wl.y * wl.y + wl.z * wl.z + wl.w * wl.w;
            short4v wb = {(short)f2bf(wl.x), (short)f2bf(wl.y),
                          (short)f2bf(wl.z), (short)f2bf(wl.w)};
            *(short4v*)&ws[row * 72 + scol] = wb;
        }
        __syncthreads();

        // ---- MFMA: 2 k-steps of 32 per chunk ----
#pragma unroll
        for (int stp = 0; stp < 2; ++stp) {
            int kb = stp * 32 + q * 8;
            short8 af = *(const short8*)&xs[(16 * wv + col) * 72 + kb];
#pragma unroll
            for (int t4 = 0; t4 < 4; ++t4) {
                short8 bf = *(const short8*)&ws[(16 * t4 + col) * 72 + kb];
                acc[t4] = __builtin_amdgcn_mfma_f32_16x16x32_bf16(af, bf, acc[t4], 0, 0, 0);
            }
        }
        __syncthreads();
    }

    // ---- reduce xsq / csq partials ----
#pragma unroll
    for (int i = 0; i < 4; ++i) {
        xsqp[srow + 16 * i][t & 15] = xacc[i];
        csqp[srow + 16 * i][t & 15] = wacc[i];
    }
    __syncthreads();
    if (t < 64) {
        float s = 0.f;
#pragma unroll
        for (int j = 0; j < 16; ++j) s += xsqp[t][j];
        xsq_s[t] = s;
    } else if (t < 128) {
        int r = t - 64;
        float s = 0.f;
#pragma unroll
        for (int j = 0; j < 16; ++j) s += csqp[r][j];
        csq_s[r] = s;
    }
    __syncthreads();

    // ---- logits + wave-parallel softmax + store ----
    // C/D layout: p = 16*t4 + col, row = 16*wv + 4*q + reg.
#pragma unroll
    for (int reg = 0; reg < 4; ++reg) {
        int row = 16 * wv + 4 * q + reg;
        float vv[4];
        float vmax = -3.4e38f;
#pragma unroll
        for (int t4 = 0; t4 < 4; ++t4) {
            int p = 16 * t4 + col;
            float v = 2.0f * acc[t4][reg] - xsq_s[row] - csq_s[p];
            v = fminf(v, 0.0f) * rbeta_s[p];
            vv[t4] = v;
            vmax = fmaxf(vmax, v);
        }
        // row's 64 p-values live in 16 lanes (same quad) x 4 tiles
#pragma unroll
        for (int off = 1; off < 16; off <<= 1)
            vmax = fmaxf(vmax, __shfl_xor(vmax, off, 64));
        float e[4], ssum = 0.f;
#pragma unroll
        for (int t4 = 0; t4 < 4; ++t4) { e[t4] = __expf(vv[t4] - vmax); ssum += e[t4]; }
#pragma unroll
        for (int off = 1; off < 16; off <<= 1)
            ssum += __shfl_xor(ssum, off, 64);
        float inv = 1.0f / ssum;
#pragma unroll
        for (int t4 = 0; t4 < 4; ++t4)
            assign[(size_t)(n0 + row) * P_ + 16 * t4 + col] = e[t4] * inv;
    }
}

// ---------------------------------------------------------------------------
// Kernel 2: out[g,p,c] += sum_n assign[n,p] * x[n,c] via bf16 MFMA.
// Both operands need k(=n)-contiguous frags but are stored n-major, so LDS
// tiles stay n-major (stride 66 bf16) and frags are built with 8 ds_read_u16
// each (bank = (k + p/2) % 32 -> 2-way only, free).
// Grid (g=8, ctile=8, split=12); atomicAdd merge of 12 K-partials.
// ---------------------------------------------------------------------------
__global__ __launch_bounds__(256) void group_mfma(
    const float* __restrict__ x,       // [N, 512]
    const float* __restrict__ assign,  // [N, 64]
    float* __restrict__ out)           // [8, 64, 512]
{
    __shared__ __align__(16) short as_[64 * 66];
    __shared__ __align__(16) short fs_[64 * 66];

    const int t    = threadIdx.x;
    const int g    = blockIdx.x;
    const int c0   = blockIdx.y * 64;
    const int kc   = blockIdx.z;        // 0..11
    const int sc   = kc >> 2;           // scale
    const int b0   = (kc & 3) * 512;    // batch offset
    const int lane = t & 63;
    const int wv   = t >> 6;            // m(p)-strip 0..3
    const int q    = lane >> 4;
    const int col  = lane & 15;
    const int srow = t >> 4;
    const int scol = (t & 15) * 4;

    const size_t base = (size_t)sc * (G_ * B_) + (size_t)g * B_ + b0;

    f32x4 acc[4];
#pragma unroll
    for (int i = 0; i < 4; ++i) acc[i] = (f32x4){0.f, 0.f, 0.f, 0.f};

    for (int ch = 0; ch < 8; ++ch) {
        // ---- stage assign-tile [n][p] and x-tile [n][c] as bf16 ----
#pragma unroll
        for (int i = 0; i < 4; ++i) {
            int n = srow + 16 * i;
            size_t nn = base + ch * 64 + n;
            f32x4 av = *(const f32x4*)(assign + nn * P_ + scol);
            unsigned a01 = (unsigned)f2bf(av.x) | ((unsigned)f2bf(av.y) << 16);
            unsigned a23 = (unsigned)f2bf(av.z) | ((unsigned)f2bf(av.w) << 16);
            *(unsigned*)&as_[n * 66 + scol]     = a01;
            *(unsigned*)&as_[n * 66 + scol + 2] = a23;

            f32x4 fv = *(const f32x4*)(x + nn * C_ + c0 + scol);
            unsigned f01 = (unsigned)f2bf(fv.x) | ((unsigned)f2bf(fv.y) << 16);
            unsigned f23 = (unsigned)f2bf(fv.z) | ((unsigned)f2bf(fv.w) << 16);
            *(unsigned*)&fs_[n * 66 + scol]     = f01;
            *(unsigned*)&fs_[n * 66 + scol + 2] = f23;
        }
        __syncthreads();

#pragma unroll
        for (int stp = 0; stp < 2; ++stp) {
            int kb = stp * 32 + q * 8;
            // A-frag: A[m=p][k=n] = assign[n][p]; lane m = 16*wv + col
            short8 af;
#pragma unroll
            for (int j = 0; j < 8; ++j) af[j] = as_[(kb + j) * 66 + 16 * wv + col];
#pragma unroll
            for (int t4 = 0; t4 < 4; ++t4) {
                // B-frag: B[k=n][n'=c]; lane n' = 16*t4 + col
                short8 bf;
#pragma unroll
                for (int j = 0; j < 8; ++j) bf[j] = fs_[(kb + j) * 66 + 16 * t4 + col];
                acc[t4] = __builtin_amdgcn_mfma_f32_16x16x32_bf16(af, bf, acc[t4], 0, 0, 0);
            }
        }
        __syncthreads();
    }

    // ---- epilogue: p = 16*wv + 4*q + reg, c = c0 + 16*t4 + col ----
#pragma unroll
    for (int t4 = 0; t4 < 4; ++t4) {
#pragma unroll
        for (int reg = 0; reg < 4; ++reg) {
            int p = 16 * wv + 4 * q + reg;
            int c = c0 + 16 * t4 + col;
            atomicAdd(&out[(size_t)g * (P_ * C_) + (size_t)p * C_ + c], acc[t4][reg]);
        }
    }
}

// ---------------------------------------------------------------------------
extern "C" void kernel_launch(void* const* d_in, const int* in_sizes, int n_in,
                              void* d_out, int out_size, void* d_ws, size_t ws_size,
                              hipStream_t stream) {
    const float* x  = (const float*)d_in[0];   // node_feats [3, 16384, 512]
    const float* w  = (const float*)d_in[1];   // weight [64, 512]
    const float* sf = (const float*)d_in[2];   // smooth_factor [64]

    float* out    = (float*)d_out;              // outputs [8, 64, 512]
    float* assign = out + (size_t)G_ * P_ * C_; // assign [N, 64]

    zero_kernel<<<(G_ * P_ * C_ + 255) / 256, 256, 0, stream>>>(out, G_ * P_ * C_);

    assign_mfma<<<N_ / 64, 256, 0, stream>>>(x, w, sf, assign);

    dim3 gridB(G_, C_ / 64, 12);
    group_mfma<<<gridB, 256, 0, stream>>>(x, assign, out);
}

// Round 3
// 194.292 us; speedup vs baseline: 1.5289x; 1.0247x over previous
//
#include <hip/hip_runtime.h>
#include <math.h>

#define S_ 3
#define G_ 8
#define B_ 2048
#define C_ 512
#define P_ 64
#define N_ (S_ * G_ * B_)   // 49152

typedef __attribute__((ext_vector_type(8))) short short8;
typedef __attribute__((ext_vector_type(4))) float f32x4;
typedef __attribute__((ext_vector_type(4))) unsigned int uint4v;
typedef __attribute__((ext_vector_type(2))) unsigned int uint2v;

__device__ __forceinline__ unsigned f2bf1(float f) {
    union { float f; unsigned u; } c; c.f = f;
    unsigned u = c.u;
    u += 0x7fffu + ((u >> 16) & 1u);   // RNE
    return u >> 16;
}
__device__ __forceinline__ unsigned pk2(float a, float b) {
    return f2bf1(a) | (f2bf1(b) << 16);
}

// ---------------------------------------------------------------------------
// Kernel 0: zero the outputs accumulator region (harness poisons d_out 0xAA)
// ---------------------------------------------------------------------------
__global__ void zero_kernel(float* __restrict__ out) {
    int i = blockIdx.x * blockDim.x + threadIdx.x;   // 65536 float4 slots
    ((f32x4*)out)[i] = (f32x4){0.f, 0.f, 0.f, 0.f};
}

// ---------------------------------------------------------------------------
// Kernel 1: prep — w -> bf16 (row-major, k-contiguous), csq[p], rbeta[p]=1/sigmoid
// 64 blocks x 64 threads (one wave per p-row).
// ---------------------------------------------------------------------------
__global__ __launch_bounds__(64) void prep_kernel(
    const float* __restrict__ w, const float* __restrict__ sf,
    unsigned short* __restrict__ wb, float* __restrict__ csq,
    float* __restrict__ rbeta)
{
    const int p = blockIdx.x, l = threadIdx.x;
    const float* wr = w + (size_t)p * C_ + l * 8;
    f32x4 a = *(const f32x4*)wr;
    f32x4 b = *(const f32x4*)(wr + 4);
    float s = a[0]*a[0] + a[1]*a[1] + a[2]*a[2] + a[3]*a[3]
            + b[0]*b[0] + b[1]*b[1] + b[2]*b[2] + b[3]*b[3];
    uint4v pk;
    pk.x = pk2(a[0], a[1]); pk.y = pk2(a[2], a[3]);
    pk.z = pk2(b[0], b[1]); pk.w = pk2(b[2], b[3]);
    *(uint4v*)&wb[(size_t)p * C_ + l * 8] = pk;
#pragma unroll
    for (int off = 1; off < 64; off <<= 1) s += __shfl_xor(s, off, 64);
    if (l == 0) csq[p] = s;
    if (p == 0) rbeta[l] = 1.0f + expf(-sf[l]);
}

// ---------------------------------------------------------------------------
// Kernel 2: assign via bf16 MFMA with ZERO LDS in the main loop.
// A-frag: direct global load of x (lane row = n0+16*wv+col, k contiguous).
// B-frag: direct load of bf16 w (L1/L2-resident).
// |x|^2 fused into the A loads, reduced with shuffles.
// Epilogue: softmax (shuffle), write assign fp32 + transposed bf16 a_t[p][n].
// ---------------------------------------------------------------------------
__global__ __launch_bounds__(256) void assign_v2(
    const float* __restrict__ x, const unsigned short* __restrict__ wb,
    const float* __restrict__ csq, const float* __restrict__ rbeta,
    float* __restrict__ assign, unsigned short* __restrict__ a_t)
{
    __shared__ float lg[64 * 68];   // [row][p], stride 68 for 2-way banks

    const int t    = threadIdx.x;
    const int lane = t & 63;
    const int wv   = t >> 6;
    const int q    = lane >> 4;
    const int col  = lane & 15;
    const int n0   = blockIdx.x * 64;
    const int myrow = 16 * wv + col;

    const float* xr = x + (size_t)(n0 + myrow) * C_ + q * 8;

    float csqv[4], rbv[4];
#pragma unroll
    for (int t4 = 0; t4 < 4; ++t4) {
        csqv[t4] = csq[16 * t4 + col];
        rbv[t4]  = rbeta[16 * t4 + col];
    }

    f32x4 acc[4];
#pragma unroll
    for (int i = 0; i < 4; ++i) acc[i] = (f32x4){0.f, 0.f, 0.f, 0.f};
    float xsq = 0.f;

#pragma unroll
    for (int ks = 0; ks < 16; ++ks) {
        f32x4 a = *(const f32x4*)(xr + ks * 32);
        f32x4 b = *(const f32x4*)(xr + ks * 32 + 4);
        xsq += a[0]*a[0] + a[1]*a[1] + a[2]*a[2] + a[3]*a[3]
             + b[0]*b[0] + b[1]*b[1] + b[2]*b[2] + b[3]*b[3];
        union { uint4v u; short8 s; } cvt;
        cvt.u.x = pk2(a[0], a[1]); cvt.u.y = pk2(a[2], a[3]);
        cvt.u.z = pk2(b[0], b[1]); cvt.u.w = pk2(b[2], b[3]);
        short8 af = cvt.s;
#pragma unroll
        for (int t4 = 0; t4 < 4; ++t4) {
            short8 bf = *(const short8*)&wb[(size_t)(16 * t4 + col) * C_ + ks * 32 + q * 8];
            acc[t4] = __builtin_amdgcn_mfma_f32_16x16x32_bf16(af, bf, acc[t4], 0, 0, 0);
        }
    }

    // full |x|^2 per row: combine the 4 q-partials, then gather per D-row
    xsq += __shfl_xor(xsq, 16, 64);
    xsq += __shfl_xor(xsq, 32, 64);
    float xsqr[4];
#pragma unroll
    for (int reg = 0; reg < 4; ++reg) xsqr[reg] = __shfl(xsq, 4 * q + reg, 64);

#pragma unroll
    for (int reg = 0; reg < 4; ++reg) {
        const int row = 16 * wv + 4 * q + reg;
        float vv[4], vmax = -3.4e38f;
#pragma unroll
        for (int t4 = 0; t4 < 4; ++t4) {
            float v = 2.0f * acc[t4][reg] - xsqr[reg] - csqv[t4];
            v = fminf(v, 0.0f) * rbv[t4];
            vv[t4] = v;
            vmax = fmaxf(vmax, v);
        }
#pragma unroll
        for (int off = 1; off < 16; off <<= 1)
            vmax = fmaxf(vmax, __shfl_xor(vmax, off, 64));
        float e[4], ss = 0.f;
#pragma unroll
        for (int t4 = 0; t4 < 4; ++t4) { e[t4] = __expf(vv[t4] - vmax); ss += e[t4]; }
#pragma unroll
        for (int off = 1; off < 16; off <<= 1)
            ss += __shfl_xor(ss, off, 64);
        const float inv = 1.0f / ss;
#pragma unroll
        for (int t4 = 0; t4 < 4; ++t4) {
            const float val = e[t4] * inv;
            assign[(size_t)(n0 + row) * P_ + 16 * t4 + col] = val;
            lg[row * 68 + 16 * t4 + col] = val;
        }
    }
    __syncthreads();

    // transposed bf16 copy for the group kernel: a_t[p][n]
    const int p  = t >> 2;       // 0..63
    const int nq = t & 3;        // 16-n segment
    float v[16];
#pragma unroll
    for (int i = 0; i < 16; ++i) v[i] = lg[(nq * 16 + i) * 68 + p];
    uint4v d0, d1;
    d0.x = pk2(v[0], v[1]);  d0.y = pk2(v[2], v[3]);
    d0.z = pk2(v[4], v[5]);  d0.w = pk2(v[6], v[7]);
    d1.x = pk2(v[8], v[9]);  d1.y = pk2(v[10], v[11]);
    d1.z = pk2(v[12], v[13]); d1.w = pk2(v[14], v[15]);
    unsigned short* dst = a_t + (size_t)p * N_ + n0 + nq * 16;
    *(uint4v*)dst = d0;
    *(uint4v*)(dst + 8) = d1;
}

// ---------------------------------------------------------------------------
// Kernel 3: out[g,p,c] += sum_n a[n,p] x[n,c] via bf16 MFMA.
// A-frags direct from a_t[p][n] (global, k=n contiguous).
// x-tile LDS-staged TRANSPOSED (register 4x4 transpose + XOR swizzle) so
// B-frag reads are ds_read_b128 at <=2-way banks.
// Grid (g=8, ctile=8, split=12); atomicAdd merge.
// ---------------------------------------------------------------------------
__global__ __launch_bounds__(256) void group_v3(
    const float* __restrict__ x, const unsigned short* __restrict__ a_t,
    float* __restrict__ out)
{
    __shared__ unsigned int fsu[64 * 36];   // [c][n-pairs], swizzled, 9216 B

    const int t    = threadIdx.x;
    const int lane = t & 63;
    const int wv   = t >> 6;
    const int q    = lane >> 4;
    const int col  = lane & 15;
    const int g    = blockIdx.x;
    const int c0   = blockIdx.y * 64;
    const int kc   = blockIdx.z;
    const int sc   = kc >> 2;
    const int b0   = (kc & 3) * 512;
    const int srow = t >> 4;    // 0..15
    const int scol = t & 15;    // 0..15

    const size_t base = (size_t)sc * (G_ * B_) + (size_t)g * B_ + b0;
    const unsigned short* at_row = a_t + (size_t)(16 * wv + col) * N_ + base;

    f32x4 acc[4];
#pragma unroll
    for (int i = 0; i < 4; ++i) acc[i] = (f32x4){0.f, 0.f, 0.f, 0.f};

    for (int ch = 0; ch < 8; ++ch) {
        const int nb = ch * 64;
        // ---- stage x-tile transposed: 4x4 register transpose, pair-packed ----
        const size_t rbase = (base + nb + srow * 4) * C_ + c0 + scol * 4;
        f32x4 m0 = *(const f32x4*)(x + rbase);
        f32x4 m1 = *(const f32x4*)(x + rbase + C_);
        f32x4 m2 = *(const f32x4*)(x + rbase + 2 * C_);
        f32x4 m3 = *(const f32x4*)(x + rbase + 3 * C_);
        const int sw_w = (scol & 6) << 3;           // swizzle from c>>2 bits 1..2
        const int nsw  = (srow * 4) ^ sw_w;
#pragma unroll
        for (int cc = 0; cc < 4; ++cc) {
            uint2v u;
            u.x = pk2(m0[cc], m1[cc]);
            u.y = pk2(m2[cc], m3[cc]);
            const int cl = scol * 4 + cc;
            *(uint2v*)&fsu[cl * 36 + (nsw >> 1)] = u;
        }
        __syncthreads();

#pragma unroll
        for (int stp = 0; stp < 2; ++stp) {
            const int kb = stp * 32 + q * 8;
            short8 af = *(const short8*)(at_row + nb + kb);
#pragma unroll
            for (int t4 = 0; t4 < 4; ++t4) {
                const int c  = 16 * t4 + col;
                const int sw = ((c >> 2) & 6) << 3;
                short8 bf = *(const short8*)&fsu[c * 36 + ((kb ^ sw) >> 1)];
                acc[t4] = __builtin_amdgcn_mfma_f32_16x16x32_bf16(af, bf, acc[t4], 0, 0, 0);
            }
        }
        __syncthreads();
    }

#pragma unroll
    for (int t4 = 0; t4 < 4; ++t4) {
#pragma unroll
        for (int reg = 0; reg < 4; ++reg) {
            const int p = 16 * wv + 4 * q + reg;
            const int c = c0 + 16 * t4 + col;
            atomicAdd(&out[(size_t)g * (P_ * C_) + (size_t)p * C_ + c], acc[t4][reg]);
        }
    }
}

// ---------------------------------------------------------------------------
extern "C" void kernel_launch(void* const* d_in, const int* in_sizes, int n_in,
                              void* d_out, int out_size, void* d_ws, size_t ws_size,
                              hipStream_t stream) {
    const float* x  = (const float*)d_in[0];   // node_feats [3, 16384, 512]
    const float* w  = (const float*)d_in[1];   // weight [64, 512]
    const float* sf = (const float*)d_in[2];   // smooth_factor [64]

    float* out    = (float*)d_out;              // outputs [8, 64, 512]
    float* assign = out + (size_t)G_ * P_ * C_; // assign [N, 64] fp32

    // workspace layout
    unsigned short* wb    = (unsigned short*)d_ws;                 // 65536 B
    float*          csq   = (float*)((char*)d_ws + 65536);         // 256 B
    float*          rbeta = (float*)((char*)d_ws + 65792);         // 256 B
    unsigned short* a_t   = (unsigned short*)((char*)d_ws + 66048);// 64*49152*2 B

    zero_kernel<<<(G_ * P_ * C_) / (4 * 256), 256, 0, stream>>>(out);
    prep_kernel<<<P_, 64, 0, stream>>>(w, sf, wb, csq, rbeta);
    assign_v2<<<N_ / 64, 256, 0, stream>>>(x, wb, csq, rbeta, assign, a_t);
    dim3 gridB(G_, C_ / 64, 12);
    group_v3<<<gridB, 256, 0, stream>>>(x, a_t, out);
}